// Round 3
// baseline (50.800 us; speedup 1.0000x reference)
//
#include <hip/hip_runtime.h>
#include <math.h>

#define HDIM 2048
#define NEXP 8
#define TB 2                         // tokens per wave
#define BLOCK 1024
#define WAVES_PB (BLOCK / 64)        // 16
#define TOK_PB (WAVES_PB * TB)       // 32 tokens per block

// ---------------------------------------------------------------------------
// One wave handles TB=2 tokens. Lanes split H (float4 each); each lane
// accumulates partials for all 16 (token,expert) pairs; W is processed in
// two 4-expert halves per iter to keep VGPR <= 64 (target: 8 waves/SIMD).
// Shuffle fold leaves lane l (l<16) holding logit(token (l>>3)&1, expert
// l&7). Top-2 + softmax in-register; histogram via LDS + 8 float atomics
// per block.
// ---------------------------------------------------------------------------
__global__ __launch_bounds__(BLOCK, 8) void
router_main(const float* __restrict__ x,
            const float* __restrict__ W,
            float* __restrict__ out_scores,   // [T,2]
            float* __restrict__ out_idx,      // [T,2] as float
            float* __restrict__ hist,         // [8], pre-zeroed
            int T)
{
    __shared__ int cnt[NEXP];
    if (threadIdx.x < NEXP) cnt[threadIdx.x] = 0;
    __syncthreads();

    const int lane = threadIdx.x & 63;
    const int wv   = threadIdx.x >> 6;
    const int tok0 = blockIdx.x * TOK_PB + wv * TB;

    int t0 = tok0 + 0; if (t0 > T - 1) t0 = T - 1;
    int t1 = tok0 + 1; if (t1 > T - 1) t1 = T - 1;
    const float* xb0 = x + (size_t)t0 * HDIM + lane * 4;
    const float* xb1 = x + (size_t)t1 * HDIM + lane * 4;
    const float* wb  = W + lane * 4;

    float acc[16];
#pragma unroll
    for (int i = 0; i < 16; ++i) acc[i] = 0.f;

#pragma unroll
    for (int iter = 0; iter < HDIM / 256; ++iter) {
        const int h = iter * 256;
        const float4 x0 = *reinterpret_cast<const float4*>(xb0 + h);
        const float4 x1 = *reinterpret_cast<const float4*>(xb1 + h);
#pragma unroll
        for (int half = 0; half < 2; ++half) {
            const int b = half * 4;
            const float4 w0 = *reinterpret_cast<const float4*>(wb + (size_t)(b + 0) * HDIM + h);
            const float4 w1 = *reinterpret_cast<const float4*>(wb + (size_t)(b + 1) * HDIM + h);
            const float4 w2 = *reinterpret_cast<const float4*>(wb + (size_t)(b + 2) * HDIM + h);
            const float4 w3 = *reinterpret_cast<const float4*>(wb + (size_t)(b + 3) * HDIM + h);
            acc[b+0]   = fmaf(x0.w, w0.w, fmaf(x0.z, w0.z, fmaf(x0.y, w0.y, fmaf(x0.x, w0.x, acc[b+0]))));
            acc[b+1]   = fmaf(x0.w, w1.w, fmaf(x0.z, w1.z, fmaf(x0.y, w1.y, fmaf(x0.x, w1.x, acc[b+1]))));
            acc[b+2]   = fmaf(x0.w, w2.w, fmaf(x0.z, w2.z, fmaf(x0.y, w2.y, fmaf(x0.x, w2.x, acc[b+2]))));
            acc[b+3]   = fmaf(x0.w, w3.w, fmaf(x0.z, w3.z, fmaf(x0.y, w3.y, fmaf(x0.x, w3.x, acc[b+3]))));
            acc[b+8]   = fmaf(x1.w, w0.w, fmaf(x1.z, w0.z, fmaf(x1.y, w0.y, fmaf(x1.x, w0.x, acc[b+8]))));
            acc[b+9]   = fmaf(x1.w, w1.w, fmaf(x1.z, w1.z, fmaf(x1.y, w1.y, fmaf(x1.x, w1.x, acc[b+9]))));
            acc[b+10]  = fmaf(x1.w, w2.w, fmaf(x1.z, w2.z, fmaf(x1.y, w2.y, fmaf(x1.x, w2.x, acc[b+10]))));
            acc[b+11]  = fmaf(x1.w, w3.w, fmaf(x1.z, w3.z, fmaf(x1.y, w3.y, fmaf(x1.x, w3.x, acc[b+11]))));
        }
    }

    // ---- reduce 16 partial sums across 64 lanes (all static indices) ----
#pragma unroll
    for (int j = 0; j < 16; ++j) acc[j] += __shfl_xor(acc[j], 32, 64);
#pragma unroll
    for (int j = 0; j < 16; ++j) acc[j] += __shfl_xor(acc[j], 16, 64);

#define FOLD(SM)                                                          \
    {                                                                     \
        const bool up = (lane & SM) != 0;                                 \
        _Pragma("unroll")                                                 \
        for (int j = 0; j < SM; ++j) {                                    \
            float keep = up ? acc[j + SM] : acc[j];                       \
            float send = up ? acc[j] : acc[j + SM];                       \
            acc[j] = keep + __shfl_xor(send, SM, 64);                     \
        }                                                                 \
    }
    FOLD(8) FOLD(4) FOLD(2) FOLD(1)
#undef FOLD

    // lane l (any l) holds logit(token tok0 + ((l>>3)&1), expert l&7)
    const int e_my  = lane & 7;
    const int t_loc = (lane >> 3) & 1;
    const float mylg = acc[0];

    // ---- top-1 within each aligned 8-lane group (tie -> lower index) ----
    float v1 = mylg;
    int   i1 = e_my;
#pragma unroll
    for (int m = 1; m <= 4; m <<= 1) {
        float ov = __shfl_xor(v1, m, 64);
        int   oi = __shfl_xor(i1, m, 64);
        if (ov > v1 || (ov == v1 && oi < i1)) { v1 = ov; i1 = oi; }
    }
    // ---- top-2: exclude i1, repeat ----
    float v2 = (e_my == i1) ? -3.402823466e+38f : mylg;
    int   i2 = e_my;
#pragma unroll
    for (int m = 1; m <= 4; m <<= 1) {
        float ov = __shfl_xor(v2, m, 64);
        int   oi = __shfl_xor(i2, m, 64);
        if (ov > v2 || (ov == v2 && oi < i2)) { v2 = ov; i2 = oi; }
    }

    // ---- softmax over the 2 selected logits (fp32, stable: v1 >= v2) ----
    const float ed  = expf(v2 - v1);
    const float inv = 1.0f / (1.0f + ed);

    const int tok = tok0 + t_loc;
    if (lane < 16 && e_my == 0 && tok < T) {
        *reinterpret_cast<float2*>(out_scores + 2 * tok) = make_float2(inv, ed * inv);
        *reinterpret_cast<float2*>(out_idx    + 2 * tok) = make_float2((float)i1, (float)i2);
        atomicAdd(&cnt[i1], 1);
        atomicAdd(&cnt[i2], 1);
    }

    __syncthreads();
    // integer-valued float adds are exact (< 2^24) -> order-independent,
    // deterministic. 512 atomics per expert address, spread over the kernel.
    if (threadIdx.x < NEXP)
        atomicAdd(&hist[threadIdx.x], (float)cnt[threadIdx.x]);
}

extern "C" void kernel_launch(void* const* d_in, const int* in_sizes, int n_in,
                              void* d_out, int out_size, void* d_ws, size_t ws_size,
                              hipStream_t stream)
{
    const float* x = (const float*)d_in[0];
    const float* W = (const float*)d_in[1];
    const int T = in_sizes[0] / HDIM;          // 16384

    float* out        = (float*)d_out;
    float* out_scores = out;                   // [T,2]
    float* out_idx    = out + (size_t)2 * T;   // [T,2]
    float* hist       = out + (size_t)4 * T;   // [8]

    // zero the 8 hist slots every call (atomics accumulate into them)
    hipMemsetAsync(hist, 0, NEXP * sizeof(float), stream);

    const int nblocks = (T + TOK_PB - 1) / TOK_PB;   // 512
    router_main<<<nblocks, BLOCK, 0, stream>>>(x, W, out_scores, out_idx, hist, T);
}